// Round 4
// baseline (377.918 us; speedup 1.0000x reference)
//
#include <hip/hip_runtime.h>
#include <hip/hip_bf16.h>

// RNN: B=1024, T=512, H=128, +4 autoregressive steps -> out (1024, 516)
// Round 4: shorten the per-step serial dependency chain (round 3 was
// latency-bound at 1310 cyc/step, MfmaUtil 4.8%, VALUBusy 10.6%).
//  - y deferred: decoder partials -> LDS pq (dbl-buffered); y[t-1] computed
//    off-chain next step into LDS ybuf; on-chain feedback only for t>=512.
//  - NO global loads/stores inside the step loop (out flushed at the end)
//    -> barrier waitcnt is lgkm-only, no HBM store-ack on the chain.
//  - xv register-prefetched one step ahead.
//  - MFMA accumulation chains split depth 4 -> 2 (paired kf accumulators).
//  - __shared__ hoisted out of the template (was duplicated: 84KB -> 76KB).

#define BB 1024
#define TT 512
#define HH 128
#define TOUT 516
#define BM 16          // batch rows per block
#define NW 4           // waves per block
#define MTW 2          // 16-row m-tiles per wave (4*2*16 = 128 = HH)
#define HSTR 136       // padded h stride in bf16 elems (272 B, 17 x 16B: odd)
#define XSTR 513       // xs stride (odd dwords)
#define YSTR 517       // ybuf stride (gcd(5,32)=1 bank spread)

typedef __attribute__((ext_vector_type(8))) short bf16x8;
typedef __attribute__((ext_vector_type(4))) short short4_t;
typedef __attribute__((ext_vector_type(4))) float f32x4;

__device__ __forceinline__ short f2bs(float f) {
    __hip_bfloat16 h = __float2bfloat16(f);
    return __builtin_bit_cast(short, h);
}
__device__ __forceinline__ float bs2f(short s) {
    __hip_bfloat16 h = __builtin_bit_cast(__hip_bfloat16, s);
    return __bfloat162float(h);
}

__global__ void detect_dtype(const void* w, int* flag) {
    const int lane = threadIdx.x;  // 64 threads
    const __hip_bfloat16* p = (const __hip_bfloat16*)w;
    const float v0 = __bfloat162float(p[lane]);
    const float v1 = __bfloat162float(p[64 + lane]);
    const bool bad = !(fabsf(v0) < 100.0f) || !(fabsf(v1) < 100.0f);
    const unsigned long long m = __ballot(bad);
    if (lane == 0) *flag = (__popcll(m) > 4) ? 1 : 0;  // 1 => data is fp32
}

template <bool F32>
__device__ __forceinline__ float ldg(const void* p, int idx) {
    if (F32) return ((const float*)p)[idx];
    return __bfloat162float(((const __hip_bfloat16*)p)[idx]);
}

template <bool F32>
__device__ void rnn_body(const void* __restrict__ xg, const void* __restrict__ h0,
                         const void* __restrict__ w0, const void* __restrict__ b0,
                         const void* __restrict__ W,  const void* __restrict__ bw,
                         const void* __restrict__ dw, const void* __restrict__ db,
                         void* __restrict__ out,
                         float (*xs)[XSTR], float (*ybuf)[YSTR],
                         __hip_bfloat16 (*hbuf)[BM][HSTR], float (*pq)[4])
{
    const int tid  = threadIdx.x;
    const int lane = tid & 63;
    const int wv   = tid >> 6;        // 0..3
    const int q    = lane >> 4;       // 0..3
    const int n    = lane & 15;       // batch col
    const int row0 = blockIdx.x * BM;

    // stage x (fp32 in LDS)
    for (int idx = tid; idx < BM * TT; idx += 256) {
        const int rr = idx >> 9, t2 = idx & (TT - 1);
        xs[rr][t2] = ldg<F32>(xg, (row0 + rr) * TT + t2);
    }
    // stage h0 as bf16
    for (int idx = tid; idx < BM * HH; idx += 256) {
        const int rr = idx >> 7, ii = idx & (HH - 1);
        hbuf[0][rr][ii] = __float2bfloat16(ldg<F32>(h0, (row0 + rr) * HH + ii));
    }

    // preload W fragments (A-operand: A[m=lane&15][k=q*8+j]), hi/lo split
    bf16x8 wa_hi[MTW][4], wa_lo[MTW][4];
    #pragma unroll
    for (int m2 = 0; m2 < MTW; ++m2) {
        const int ia = (wv * MTW + m2) * 16 + n;           // W row (output unit)
        #pragma unroll
        for (int kf = 0; kf < 4; ++kf) {
            const int kb = kf * 32 + q * 8;
            bf16x8 hi, lo;
            #pragma unroll
            for (int j = 0; j < 8; ++j) {
                const float f = ldg<F32>(W, ia * HH + kb + j);
                const short hs = f2bs(f);
                hi[j] = hs;
                lo[j] = F32 ? f2bs(f - bs2f(hs)) : (short)0;
            }
            wa_hi[m2][kf] = hi;
            wa_lo[m2][kf] = lo;
        }
    }
    // epilogue constants (C-layout rows: i = mt*16 + q*4 + r)
    float bsum[MTW][4], w0v[MTW][4], decv[MTW][4];
    #pragma unroll
    for (int m2 = 0; m2 < MTW; ++m2)
        #pragma unroll
        for (int r = 0; r < 4; ++r) {
            const int ic = (wv * MTW + m2) * 16 + q * 4 + r;
            bsum[m2][r] = ldg<F32>(b0, ic) + ldg<F32>(bw, ic);
            w0v[m2][r]  = ldg<F32>(w0, ic);
            decv[m2][r] = ldg<F32>(dw, ic);
        }
    const float dbv = ldg<F32>(db, 0);

    __syncthreads();

    int cur = 0;
    float xv_pref = xs[n][0];
    #pragma unroll 1
    for (int t = 0; t < TOUT; ++t) {
        // B-fragments first (longest-latency on-chain load)
        bf16x8 bfrag[4];
        #pragma unroll
        for (int kf = 0; kf < 4; ++kf)
            bfrag[kf] = *(const bf16x8*)&hbuf[cur][n][kf * 32 + q * 8];

        // step input: prefetched x, or (t>=TT) on-chain y[t-1] from pq
        float xv;
        if (t < TT) {
            xv = xv_pref;
        } else {
            const f32x4 v = *(const f32x4*)&pq[((t - 1) & 1) * BM + n][0];
            xv = v[0] + v[1] + v[2] + v[3] + dbv;
        }
        if (t + 1 < TT) xv_pref = xs[n][t + 1];   // off-chain prefetch

        // deferred y writer (off-chain): wave 1, q==0 lanes emit y[t-1]
        if (wv == 1 && q == 0 && t > 0) {
            const f32x4 v = *(const f32x4*)&pq[((t - 1) & 1) * BM + n][0];
            ybuf[n][t - 1] = v[0] + v[1] + v[2] + v[3] + dbv;
        }

        f32x4 acc[MTW][2][2];   // [m-tile][hi/lo][kf-half], depth-2 chains
        #pragma unroll
        for (int m2 = 0; m2 < MTW; ++m2)
            #pragma unroll
            for (int hl = 0; hl < 2; ++hl)
                #pragma unroll
                for (int hf = 0; hf < 2; ++hf)
                    acc[m2][hl][hf] = (f32x4){0.f, 0.f, 0.f, 0.f};

        #pragma unroll
        for (int kf = 0; kf < 4; ++kf) {
            const int hf = kf >> 1;
            #pragma unroll
            for (int m2 = 0; m2 < MTW; ++m2) {
                acc[m2][0][hf] = __builtin_amdgcn_mfma_f32_16x16x32_bf16(
                    wa_hi[m2][kf], bfrag[kf], acc[m2][0][hf], 0, 0, 0);
                if (F32)
                    acc[m2][1][hf] = __builtin_amdgcn_mfma_f32_16x16x32_bf16(
                        wa_lo[m2][kf], bfrag[kf], acc[m2][1][hf], 0, 0, 0);
            }
        }

        // epilogue: z -> tanh -> pack bf16 -> decoder partial
        float p = 0.0f;
        #pragma unroll
        for (int m2 = 0; m2 < MTW; ++m2) {
            short4_t pk;
            #pragma unroll
            for (int r = 0; r < 4; ++r) {
                const float z = (acc[m2][0][0][r] + acc[m2][0][1][r])
                              + (acc[m2][1][0][r] + acc[m2][1][1][r])
                              + fmaf(xv, w0v[m2][r], bsum[m2][r]);
                const float e = __expf(z + z);
                const float h = 1.0f - 2.0f * __builtin_amdgcn_rcpf(e + 1.0f);
                p = fmaf(decv[m2][r], h, p);
                pk[r] = f2bs(h);
            }
            *(short4_t*)&hbuf[cur ^ 1][n][(wv * MTW + m2) * 16 + q * 4] = pk;
        }
        p += __shfl_xor(p, 16);
        p += __shfl_xor(p, 32);
        if (q == 0) pq[(t & 1) * BM + n][wv] = p;
        __syncthreads();
        cur ^= 1;
    }

    // tail: y[515]
    if (wv == 1 && q == 0) {
        const f32x4 v = *(const f32x4*)&pq[((TOUT - 1) & 1) * BM + n][0];
        ybuf[n][TOUT - 1] = v[0] + v[1] + v[2] + v[3] + dbv;
    }
    __syncthreads();

    // flush outputs (coalesced over t)
    for (int r = 0; r < BM; ++r)
        for (int t2 = tid; t2 < TOUT; t2 += 256) {
            const int o = (row0 + r) * TOUT + t2;
            const float y = ybuf[r][t2];
            if (F32) ((float*)out)[o] = y;
            else     ((__hip_bfloat16*)out)[o] = __float2bfloat16(y);
        }
}

__global__ __launch_bounds__(256, 1)
void rnn_mfma(const void* __restrict__ xg, const void* __restrict__ h0,
              const void* __restrict__ w0, const void* __restrict__ b0,
              const void* __restrict__ W,  const void* __restrict__ bw,
              const void* __restrict__ dw, const void* __restrict__ db,
              void* __restrict__ out, const int* __restrict__ flag)
{
    __shared__ float xs[BM][XSTR];                          // 32.8 KB
    __shared__ float ybuf[BM][YSTR];                        // 33.1 KB
    __shared__ __align__(16) __hip_bfloat16 hbuf[2][BM][HSTR]; // 8.7 KB
    __shared__ __align__(16) float pq[2 * BM][4];           // 0.5 KB

    const int f = *(volatile const int*)flag;  // block-uniform
    if (f) rnn_body<true >(xg, h0, w0, b0, W, bw, dw, db, out, xs, ybuf, hbuf, pq);
    else   rnn_body<false>(xg, h0, w0, b0, W, bw, dw, db, out, xs, ybuf, hbuf, pq);
}

extern "C" void kernel_launch(void* const* d_in, const int* in_sizes, int n_in,
                              void* d_out, int out_size, void* d_ws, size_t ws_size,
                              hipStream_t stream) {
    int* flag = (int*)d_ws;
    detect_dtype<<<1, 64, 0, stream>>>(d_in[4], flag);  // probe fc_w
    rnn_mfma<<<BB / BM, 256, 0, stream>>>(d_in[0], d_in[1], d_in[2], d_in[3],
                                          d_in[4], d_in[5], d_in[6], d_in[7],
                                          d_out, flag);
}